// Round 1
// baseline (889.400 us; speedup 1.0000x reference)
//
#include <hip/hip_runtime.h>
#include <cstdint>
#include <cstddef>

// ---------------------------------------------------------------------------
// RSSM cell on MI355X. f32 I/O, bf16 MFMA compute.
// B=1024, S=1024, D=2048, E=2048, CTX=1024, OBS=2048.
// ---------------------------------------------------------------------------

typedef __attribute__((ext_vector_type(4))) float f32x4;
typedef __attribute__((ext_vector_type(4))) unsigned short u16x4;
typedef __attribute__((ext_vector_type(8))) __bf16 bf16x8;

__device__ __forceinline__ unsigned short f32_to_bf16(float f) {
  union { float f; uint32_t u; } v; v.f = f;
  uint32_t u = v.u;
  u += 0x7fffu + ((u >> 16) & 1u);   // RNE
  return (unsigned short)(u >> 16);
}

__device__ __forceinline__ void gload_lds16(const void* g, void* s) {
  __builtin_amdgcn_global_load_lds(
      (const __attribute__((address_space(1))) void*)g,
      (__attribute__((address_space(3))) void*)s, 16, 0, 0);
}

// ---------------------------------------------------------------------------
// GEMM: C[M][N] = act(A[M][K](bf16) @ Bt[N][K](bf16)^T + bias[N])
// 128x128 tile, 4 waves (2x2 of 64x64), BK=64, mfma_f32_16x16x32_bf16.
// m97-structure: global_load_lds w16 staging, single LDS buffer, 2 barriers.
// ---------------------------------------------------------------------------
template<bool RELU, bool BF16OUT>
__global__ __launch_bounds__(256)
void gemm_bt(const unsigned short* __restrict__ A, int lda,
             const unsigned short* __restrict__ Bt,
             const float* __restrict__ bias,
             float* __restrict__ Cf, unsigned short* __restrict__ Cb,
             int ldc, int K)
{
  __shared__ __align__(16) unsigned short sA[128 * 64];
  __shared__ __align__(16) unsigned short sB[128 * 64];
  const int t    = threadIdx.x;
  const int lane = t & 63;
  const int wid  = t >> 6;
  const int wr   = wid >> 1, wc = wid & 1;
  const int row0 = blockIdx.y * 128;
  const int col0 = blockIdx.x * 128;

  // staging geometry: per wave-issue, 64 lanes x 16B = 512 bf16 (8 LDS rows of 64)
  const int cbase = wid * 512 + lane * 8;
  const int rbase = cbase >> 6;     // 0..31
  const int kbase = cbase & 63;

  f32x4 acc[4][4];
  #pragma unroll
  for (int m = 0; m < 4; ++m)
    #pragma unroll
    for (int n = 0; n < 4; ++n)
      acc[m][n] = (f32x4){0.0f, 0.0f, 0.0f, 0.0f};

  const int lr = lane & 15, lg = lane >> 4;

  for (int kt = 0; kt < K; kt += 64) {
    #pragma unroll
    for (int i = 0; i < 4; ++i) {
      const int r = i * 32 + rbase;
      gload_lds16(A  + (size_t)(row0 + r) * lda + kt + kbase,
                  sA + i * 2048 + wid * 512);
      gload_lds16(Bt + (size_t)(col0 + r) * K   + kt + kbase,
                  sB + i * 2048 + wid * 512);
    }
    __syncthreads();   // drains vmcnt before barrier (compiler-inserted)
    #pragma unroll
    for (int ks = 0; ks < 2; ++ks) {
      bf16x8 av[4], bv[4];
      #pragma unroll
      for (int m = 0; m < 4; ++m)
        av[m] = *reinterpret_cast<const bf16x8*>(
                  sA + (wr * 64 + m * 16 + lr) * 64 + ks * 32 + lg * 8);
      #pragma unroll
      for (int n = 0; n < 4; ++n)
        bv[n] = *reinterpret_cast<const bf16x8*>(
                  sB + (wc * 64 + n * 16 + lr) * 64 + ks * 32 + lg * 8);
      #pragma unroll
      for (int m = 0; m < 4; ++m)
        #pragma unroll
        for (int n = 0; n < 4; ++n)
          acc[m][n] = __builtin_amdgcn_mfma_f32_16x16x32_bf16(
                        av[m], bv[n], acc[m][n], 0, 0, 0);
    }
    __syncthreads();
  }

  // epilogue: D mapping col=lane&15, row=(lane>>4)*4+reg  [m89/m91 verified]
  #pragma unroll
  for (int n = 0; n < 4; ++n) {
    const int c = col0 + wc * 64 + n * 16 + lr;
    const float b = bias ? bias[c] : 0.0f;
    #pragma unroll
    for (int m = 0; m < 4; ++m) {
      #pragma unroll
      for (int j = 0; j < 4; ++j) {
        const int r = row0 + wr * 64 + m * 16 + lg * 4 + j;
        float x = acc[m][n][j] + b;
        if (RELU) x = fmaxf(x, 0.0f);
        if (BF16OUT) Cb[(size_t)r * ldc + c] = f32_to_bf16(x);
        else         Cf[(size_t)r * ldc + c] = x;
      }
    }
  }
}

// ---------------------------------------------------------------------------
// Transpose + cast: src f32 [K][N]  ->  dst bf16 [N][K]
// ---------------------------------------------------------------------------
__global__ __launch_bounds__(256)
void transpose_cast(const float* __restrict__ src, unsigned short* __restrict__ dst,
                    int K, int N)
{
  __shared__ float tile[64][65];
  const int k0 = blockIdx.x * 64;
  const int n0 = blockIdx.y * 64;
  const int t  = threadIdx.x;
  const int lc = t & 63;
  const int rg = t >> 6;   // 0..3
  #pragma unroll
  for (int i = 0; i < 16; ++i) {
    const int r = rg * 16 + i;
    tile[r][lc] = src[(size_t)(k0 + r) * N + n0 + lc];
  }
  __syncthreads();
  #pragma unroll
  for (int i = 0; i < 16; ++i) {
    const int r = rg * 16 + i;  // local n
    dst[(size_t)(n0 + r) * K + k0 + lc] = f32_to_bf16(tile[lc][r]);
  }
}

// ---------------------------------------------------------------------------
// Strided cast f32 -> bf16 (activation assembly / concat)
// ---------------------------------------------------------------------------
__global__ __launch_bounds__(256)
void cast_rows(const float* __restrict__ src, unsigned short* __restrict__ dst,
               int cols, int dstride, int dcol)
{
  const int tid = blockIdx.x * 256 + threadIdx.x;
  const int q   = cols >> 2;
  const int row = tid / q;
  const int c   = (tid - row * q) << 2;
  f32x4 v = *reinterpret_cast<const f32x4*>(src + (size_t)row * cols + c);
  u16x4 o;
  #pragma unroll
  for (int j = 0; j < 4; ++j) o[j] = f32_to_bf16(v[j]);
  *reinterpret_cast<u16x4*>(dst + (size_t)row * dstride + dcol + c) = o;
}

// ---------------------------------------------------------------------------
// GRU elementwise: det = z*h + (1-z)*n   (gates [z,r,h], reset_after)
// gi/gh: f32 [1024][6144] (biases already in), h: f32 [1024][2048]
// ---------------------------------------------------------------------------
__global__ __launch_bounds__(256)
void gru_elem(const float* __restrict__ gi, const float* __restrict__ gh,
              const float* __restrict__ h,
              unsigned short* __restrict__ det_bf, int det_stride,
              float* __restrict__ det_out /* out+3072 base, stride 8192; may be null */)
{
  const int tid = blockIdx.x * 256 + threadIdx.x;  // 1024*512 threads
  const int row = tid >> 9;
  const int c   = (tid & 511) << 2;
  const size_t gb = (size_t)row * 6144 + c;
  f32x4 iz = *reinterpret_cast<const f32x4*>(gi + gb);
  f32x4 hz = *reinterpret_cast<const f32x4*>(gh + gb);
  f32x4 ir = *reinterpret_cast<const f32x4*>(gi + gb + 2048);
  f32x4 hr = *reinterpret_cast<const f32x4*>(gh + gb + 2048);
  f32x4 ih = *reinterpret_cast<const f32x4*>(gi + gb + 4096);
  f32x4 hh = *reinterpret_cast<const f32x4*>(gh + gb + 4096);
  f32x4 hv = *reinterpret_cast<const f32x4*>(h + (size_t)row * 2048 + c);
  f32x4 d;
  u16x4 ob;
  #pragma unroll
  for (int j = 0; j < 4; ++j) {
    const float z = 1.0f / (1.0f + expf(-(iz[j] + hz[j])));
    const float r = 1.0f / (1.0f + expf(-(ir[j] + hr[j])));
    const float n = tanhf(ih[j] + r * hh[j]);
    d[j] = z * hv[j] + (1.0f - z) * n;
    ob[j] = f32_to_bf16(d[j]);
  }
  *reinterpret_cast<u16x4*>(det_bf + (size_t)row * det_stride + c) = ob;
  if (det_out)
    *reinterpret_cast<f32x4*>(det_out + (size_t)row * 8192 + c) = d;
}

// ---------------------------------------------------------------------------
// mu/std/sample epilogue: raw f32 [1024][2048] = [mu_pre | std_pre]
// ---------------------------------------------------------------------------
__global__ __launch_bounds__(256)
void mu_std_sample(const float* __restrict__ raw, const float* __restrict__ eps,
                   float* __restrict__ out, int mu_off, int std_off, int samp_off)
{
  const int tid = blockIdx.x * 256 + threadIdx.x;  // 1024*256 threads
  const int row = tid >> 8;
  const int c   = (tid & 255) << 2;
  f32x4 mu = *reinterpret_cast<const f32x4*>(raw + (size_t)row * 2048 + c);
  f32x4 sp = *reinterpret_cast<const f32x4*>(raw + (size_t)row * 2048 + 1024 + c);
  f32x4 ev = *reinterpret_cast<const f32x4*>(eps + (size_t)row * 1024 + c);
  f32x4 sd, sm;
  #pragma unroll
  for (int j = 0; j < 4; ++j) {
    const float x = sp[j];
    const float s = ((x > 0.0f) ? (x + log1pf(expf(-x))) : log1pf(expf(x))) + 1e-4f;
    sd[j] = s;
    sm[j] = mu[j] + s * ev[j];
  }
  float* ob = out + (size_t)row * 8192;
  *reinterpret_cast<f32x4*>(ob + mu_off   + c) = mu;
  *reinterpret_cast<f32x4*>(ob + std_off  + c) = sd;
  *reinterpret_cast<f32x4*>(ob + samp_off + c) = sm;
}

// bias_cat[c] = c<1024 ? b_mu[c] : b_std[c-1024]   (colsum term added after)
__global__ __launch_bounds__(256)
void bias_init(const float* __restrict__ bmu, const float* __restrict__ bstd,
               float* __restrict__ bias)
{
  const int c = blockIdx.x * 256 + threadIdx.x;  // grid 8 -> 2048
  bias[c] = (c < 1024) ? bmu[c] : bstd[c - 1024];
}

// bias[1024+c] += 0.54 * sum_k W[k][c]   for (h2+0.54)@W_std folding
__global__ __launch_bounds__(256)
void colsum_add(const float* __restrict__ W, float* __restrict__ bias)
{
  const int c  = blockIdx.x * 256 + threadIdx.x;  // 0..1023
  const int k0 = blockIdx.y * 128;
  float s = 0.0f;
  for (int k = 0; k < 128; ++k) s += W[(size_t)(k0 + k) * 1024 + c];
  atomicAdd(bias + 1024 + c, 0.54f * s);
}

// ---------------------------------------------------------------------------

extern "C" void kernel_launch(void* const* d_in, const int* in_sizes, int n_in,
                              void* d_out, int out_size, void* d_ws, size_t ws_size,
                              hipStream_t stream)
{
  const float* obs    = (const float*)d_in[0];
  const float* ctx    = (const float*)d_in[1];
  const float* psamp  = (const float*)d_in[2];
  const float* pdet   = (const float*)d_in[3];
  // d_in[4] = reset_state: reference multiplies by ones_like -> unused
  const float* eps_p  = (const float*)d_in[5];
  const float* eps_q  = (const float*)d_in[6];
  const float* W_p1   = (const float*)d_in[7];
  const float* b_p1   = (const float*)d_in[8];
  const float* Wi     = (const float*)d_in[9];
  const float* Wh     = (const float*)d_in[10];
  const float* bi     = (const float*)d_in[11];
  const float* bh     = (const float*)d_in[12];
  const float* W_p2   = (const float*)d_in[13];
  const float* b_p2   = (const float*)d_in[14];
  const float* W_pmu  = (const float*)d_in[15];
  const float* b_pmu  = (const float*)d_in[16];
  const float* W_pstd = (const float*)d_in[17];
  const float* b_pstd = (const float*)d_in[18];
  const float* W_q1   = (const float*)d_in[19];
  const float* b_q1   = (const float*)d_in[20];
  const float* W_q2   = (const float*)d_in[21];
  const float* b_q2   = (const float*)d_in[22];
  const float* W_qmu  = (const float*)d_in[23];
  const float* b_qmu  = (const float*)d_in[24];
  const float* W_qstd = (const float*)d_in[25];
  const float* b_qstd = (const float*)d_in[26];
  float* out = (float*)d_out;

  char* ws = (char*)d_ws;
  size_t off = 0;
  auto alloc = [&](size_t bytes) -> void* {
    void* p = ws + off;
    off += (bytes + 255) & ~(size_t)255;
    return p;
  };
  typedef unsigned short us;
  us* WP1T = (us*)alloc((size_t)2048 * 2048 * 2);
  us* WIT  = (us*)alloc((size_t)6144 * 2048 * 2);
  us* WHT  = (us*)alloc((size_t)6144 * 2048 * 2);
  us* WP2T = (us*)alloc((size_t)2048 * 2048 * 2);
  us* WPST = (us*)alloc((size_t)2048 * 2048 * 2);
  us* WQ1T = (us*)alloc((size_t)2048 * 4096 * 2);
  us* WQ2T = (us*)alloc((size_t)2048 * 2048 * 2);
  us* WQST = (us*)alloc((size_t)2048 * 2048 * 2);
  us* X1   = (us*)alloc((size_t)1024 * 2048 * 2);  // [prev_sample | context]
  us* X2   = (us*)alloc((size_t)1024 * 4096 * 2);  // [det | obs]
  us* HBF  = (us*)alloc((size_t)1024 * 2048 * 2);  // prev_det_state bf16
  us* H1   = (us*)alloc((size_t)1024 * 2048 * 2);  // h1 / h1q (reused)
  us* H2   = (us*)alloc((size_t)1024 * 2048 * 2);  // h2 / h2q (reused)
  us* DETQ = (us*)alloc((size_t)1024 * 2048 * 2);
  float* GH    = (float*)alloc((size_t)1024 * 6144 * 4);
  float* GI    = (float*)alloc((size_t)1024 * 6144 * 4);
  float* RAW   = (float*)alloc((size_t)1024 * 2048 * 4);
  float* BIASP = (float*)alloc(2048 * 4);
  float* BIASQ = (float*)alloc(2048 * 4);
  (void)ws_size; (void)in_sizes; (void)n_in; (void)out_size;

  const dim3 B256(256);

  // --- weight transposes f32[K][N] -> bf16[N][K] ---
  transpose_cast<<<dim3(32, 32), B256, 0, stream>>>(W_p1, WP1T, 2048, 2048);
  transpose_cast<<<dim3(32, 96), B256, 0, stream>>>(Wi,   WIT,  2048, 6144);
  transpose_cast<<<dim3(32, 96), B256, 0, stream>>>(Wh,   WHT,  2048, 6144);
  transpose_cast<<<dim3(32, 32), B256, 0, stream>>>(W_p2, WP2T, 2048, 2048);
  transpose_cast<<<dim3(32, 16), B256, 0, stream>>>(W_pmu,  WPST,                2048, 1024);
  transpose_cast<<<dim3(32, 16), B256, 0, stream>>>(W_pstd, WPST + 1024 * 2048, 2048, 1024);
  transpose_cast<<<dim3(64, 32), B256, 0, stream>>>(W_q1, WQ1T, 4096, 2048);
  transpose_cast<<<dim3(32, 32), B256, 0, stream>>>(W_q2, WQ2T, 2048, 2048);
  transpose_cast<<<dim3(32, 16), B256, 0, stream>>>(W_qmu,  WQST,                2048, 1024);
  transpose_cast<<<dim3(32, 16), B256, 0, stream>>>(W_qstd, WQST + 1024 * 2048, 2048, 1024);

  // --- activation casts / concat ---
  cast_rows<<<dim3(1024), B256, 0, stream>>>(psamp, X1, 1024, 2048, 0);
  cast_rows<<<dim3(1024), B256, 0, stream>>>(ctx,   X1, 1024, 2048, 1024);
  cast_rows<<<dim3(2048), B256, 0, stream>>>(obs,   X2, 2048, 4096, 2048);
  cast_rows<<<dim3(2048), B256, 0, stream>>>(pdet,  HBF, 2048, 2048, 0);

  // --- fused biases for [mu|std] GEMMs: bias + 0.54*colsum(W_std) ---
  bias_init<<<dim3(8), B256, 0, stream>>>(b_pmu, b_pstd, BIASP);
  bias_init<<<dim3(8), B256, 0, stream>>>(b_qmu, b_qstd, BIASQ);
  colsum_add<<<dim3(4, 16), B256, 0, stream>>>(W_pstd, BIASP);
  colsum_add<<<dim3(4, 16), B256, 0, stream>>>(W_qstd, BIASQ);

  // --- prior chain ---
  // h1 = relu(X1 @ W_p1 + b_p1)
  gemm_bt<true, true><<<dim3(16, 8), B256, 0, stream>>>(X1, 2048, WP1T, b_p1,
                                                        nullptr, H1, 2048, 2048);
  // gh = prev_det @ Wh + bh   (shared by both GRUs)
  gemm_bt<false, false><<<dim3(48, 8), B256, 0, stream>>>(HBF, 2048, WHT, bh,
                                                          GH, nullptr, 6144, 2048);
  // gi = h1 @ Wi + bi
  gemm_bt<false, false><<<dim3(48, 8), B256, 0, stream>>>(H1, 2048, WIT, bi,
                                                          GI, nullptr, 6144, 2048);
  // det -> X2[:, :2048] (bf16) and out[:, 3072:5120] (f32)
  gru_elem<<<dim3(2048), B256, 0, stream>>>(GI, GH, pdet, X2, 4096, out + 3072);
  // h2 = relu(det @ W_p2 + b_p2)
  gemm_bt<true, true><<<dim3(16, 8), B256, 0, stream>>>(X2, 4096, WP2T, b_p2,
                                                        nullptr, H2, 2048, 2048);
  // [mu_p | std_pre_p] = h2 @ [W_pmu|W_pstd] + BIASP
  gemm_bt<false, false><<<dim3(16, 8), B256, 0, stream>>>(H2, 2048, WPST, BIASP,
                                                          RAW, nullptr, 2048, 2048);
  mu_std_sample<<<dim3(1024), B256, 0, stream>>>(RAW, eps_p, out, 0, 1024, 2048);

  // --- posterior chain ---
  // h1q = relu([det|obs] @ W_q1 + b_q1)
  gemm_bt<true, true><<<dim3(16, 8), B256, 0, stream>>>(X2, 4096, WQ1T, b_q1,
                                                        nullptr, H1, 2048, 4096);
  // giq = h1q @ Wi + bi
  gemm_bt<false, false><<<dim3(48, 8), B256, 0, stream>>>(H1, 2048, WIT, bi,
                                                          GI, nullptr, 6144, 2048);
  gru_elem<<<dim3(2048), B256, 0, stream>>>(GI, GH, pdet, DETQ, 2048, nullptr);
  // h2q = relu(detq @ W_q2 + b_q2)
  gemm_bt<true, true><<<dim3(16, 8), B256, 0, stream>>>(DETQ, 2048, WQ2T, b_q2,
                                                        nullptr, H2, 2048, 2048);
  // [mu_q | std_pre_q] = h2q @ [W_qmu|W_qstd] + BIASQ
  gemm_bt<false, false><<<dim3(16, 8), B256, 0, stream>>>(H2, 2048, WQST, BIASQ,
                                                          RAW, nullptr, 2048, 2048);
  mu_std_sample<<<dim3(1024), B256, 0, stream>>>(RAW, eps_q, out, 5120, 6144, 7168);
}

// Round 2
// 639.232 us; speedup vs baseline: 1.3914x; 1.3914x over previous
//
#include <hip/hip_runtime.h>
#include <cstdint>
#include <cstddef>

// ---------------------------------------------------------------------------
// RSSM cell on MI355X. f32 I/O, bf16 MFMA compute.
// B=1024, S=1024, D=2048, E=2048, CTX=1024, OBS=2048.
// Round 2: 2-phase prefetch dbuf GEMM, 8 waves/block, LDS XOR swizzle,
// fused transpose/cast dispatches.
// ---------------------------------------------------------------------------

typedef __attribute__((ext_vector_type(4))) float f32x4;
typedef __attribute__((ext_vector_type(4))) unsigned short u16x4;
typedef __attribute__((ext_vector_type(8))) __bf16 bf16x8;

__device__ __forceinline__ unsigned short f32_to_bf16(float f) {
  union { float f; uint32_t u; } v; v.f = f;
  uint32_t u = v.u;
  u += 0x7fffu + ((u >> 16) & 1u);   // RNE
  return (unsigned short)(u >> 16);
}

__device__ __forceinline__ void gload_lds16(const void* g, void* s) {
  __builtin_amdgcn_global_load_lds(
      (const __attribute__((address_space(1))) void*)g,
      (__attribute__((address_space(3))) void*)s, 16, 0, 0);
}

// ---------------------------------------------------------------------------
// GEMM: C[M][N] = act(A[M][K](bf16) @ Bt[N][K](bf16)^T + bias[N])
// BM=128, BK=64, BN in {64,128}. 512 threads = 8 waves (2x4), wave tile
// 64 x BN/4. Double-buffered LDS, prefetch-before-compute (T3 minimum
// 2-phase), XOR-swizzled LDS via pre-swizzled global source (rule 21).
// ---------------------------------------------------------------------------
template<int BN, bool RELU, bool BF16OUT>
__global__ __launch_bounds__(512, 4)
void gemm_bt(const unsigned short* __restrict__ A, int lda,
             const unsigned short* __restrict__ Bt,
             const float* __restrict__ bias,
             float* __restrict__ Cf, unsigned short* __restrict__ Cb,
             int ldc, int K)
{
  constexpr int ROWS = 128 + BN;       // A rows then B rows, 64 bf16 each
  constexpr int NL   = ROWS / 64;      // gload_lds rounds (512 thr x 8 el)
  constexpr int WN   = BN / 4;         // wave col width
  constexpr int NF   = WN / 16;        // n fragments per wave
  __shared__ __align__(16) unsigned short sBuf[2][ROWS * 64];

  const int t    = threadIdx.x;
  const int lane = t & 63;
  const int wid  = t >> 6;             // 0..7
  const int wr   = wid >> 2;           // 0..1
  const int wc   = wid & 3;            // 0..3
  const int row0 = blockIdx.y * 128;
  const int col0 = blockIdx.x * BN;
  const int lr   = lane & 15, lg = lane >> 4;

  // staging geometry: round i, thread t loads one 16B slot.
  // LDS lands linearly at element lin = i*4096 + t*8  (row = lin>>6, slot
  // s = (lin>>3)&7). Global source uses swizzled slot ss = s ^ (row&7), so
  // LDS slot s of row holds global slot s^(row&7)  (involution).
  const unsigned short* sptr[NL];
  int scol[NL];
  #pragma unroll
  for (int i = 0; i < NL; ++i) {
    const int lin = i * 4096 + t * 8;
    const int row = lin >> 6;
    const int s   = (lin >> 3) & 7;
    scol[i] = (s ^ (row & 7)) * 8;
    sptr[i] = (row < 128) ? (A  + (size_t)(row0 + row) * lda)
                          : (Bt + (size_t)(col0 + row - 128) * K);
  }

  auto stage = [&](int cur, int kt) {
    #pragma unroll
    for (int i = 0; i < NL; ++i)
      gload_lds16(sptr[i] + kt + scol[i], &sBuf[cur][i * 4096 + wid * 512]);
  };

  f32x4 acc[4][NF];
  #pragma unroll
  for (int m = 0; m < 4; ++m)
    #pragma unroll
    for (int n = 0; n < NF; ++n)
      acc[m][n] = (f32x4){0.0f, 0.0f, 0.0f, 0.0f};

  stage(0, 0);
  __syncthreads();                       // prologue drain: buf0 ready
  int cur = 0;
  for (int kt = 0; kt < K; kt += 64) {
    if (kt + 64 < K) stage(cur ^ 1, kt + 64);   // async prefetch next tile
    #pragma unroll
    for (int ks = 0; ks < 2; ++ks) {
      bf16x8 av[4], bv[NF];
      const int sl = ((ks * 4 + lg) ^ (lr & 7)) * 8;   // swizzled slot base
      #pragma unroll
      for (int m = 0; m < 4; ++m) {
        const int row = wr * 64 + m * 16 + lr;          // row&7 == lr&7
        av[m] = *reinterpret_cast<const bf16x8*>(&sBuf[cur][row * 64 + sl]);
      }
      #pragma unroll
      for (int n = 0; n < NF; ++n) {
        const int row = 128 + wc * WN + n * 16 + lr;    // row&7 == lr&7
        bv[n] = *reinterpret_cast<const bf16x8*>(&sBuf[cur][row * 64 + sl]);
      }
      #pragma unroll
      for (int m = 0; m < 4; ++m)
        #pragma unroll
        for (int n = 0; n < NF; ++n)
          acc[m][n] = __builtin_amdgcn_mfma_f32_16x16x32_bf16(
                        av[m], bv[n], acc[m][n], 0, 0, 0);
    }
    __syncthreads();   // drains vmcnt (prefetch landed) + guards buf reuse
    cur ^= 1;
  }

  // epilogue: D mapping col=lane&15, row=(lane>>4)*4+reg  [m89/m91 verified]
  #pragma unroll
  for (int n = 0; n < NF; ++n) {
    const int c = col0 + wc * WN + n * 16 + lr;
    const float b = bias ? bias[c] : 0.0f;
    #pragma unroll
    for (int m = 0; m < 4; ++m) {
      #pragma unroll
      for (int j = 0; j < 4; ++j) {
        const int r = row0 + wr * 64 + m * 16 + lg * 4 + j;
        float x = acc[m][n][j] + b;
        if (RELU) x = fmaxf(x, 0.0f);
        if (BF16OUT) Cb[(size_t)r * ldc + c] = f32_to_bf16(x);
        else         Cf[(size_t)r * ldc + c] = x;
      }
    }
  }
}

// ---------------------------------------------------------------------------
// Fused transpose + cast: 10 weight matrices, src f32 [K][N] -> dst bf16
// [N][K], one dispatch. Segment chosen by blockIdx range.
// ---------------------------------------------------------------------------
struct TSeg { const float* s; unsigned short* d; int N; int kshift; int t0; };
struct TArgs { TSeg g[10]; };

__global__ __launch_bounds__(256)
void transpose_all(TArgs a)
{
  __shared__ float tile[64][65];
  const int bid = blockIdx.x;
  int si = 0;
  #pragma unroll
  for (int i = 1; i < 10; ++i) if (bid >= a.g[i].t0) si = i;
  const TSeg sg = a.g[si];
  const int local = bid - sg.t0;
  const int ktiles_m1 = (1 << sg.kshift) - 1;
  const int tx = local & ktiles_m1;
  const int ty = local >> sg.kshift;
  const size_t K = (size_t)64 << sg.kshift;
  const int k0 = tx * 64;
  const int n0 = ty * 64;
  const int t  = threadIdx.x;
  const int lc = t & 63;
  const int rg = t >> 6;
  #pragma unroll
  for (int i = 0; i < 16; ++i) {
    const int r = rg * 16 + i;
    tile[r][lc] = sg.s[(size_t)(k0 + r) * sg.N + n0 + lc];
  }
  __syncthreads();
  #pragma unroll
  for (int i = 0; i < 16; ++i) {
    const int r = rg * 16 + i;  // local n
    sg.d[(size_t)(n0 + r) * K + k0 + lc] = f32_to_bf16(tile[lc][r]);
  }
}

// ---------------------------------------------------------------------------
// Fused activation casts (4 segments), one dispatch.
// ---------------------------------------------------------------------------
struct CSeg { const float* s; unsigned short* d; int qshift; int dstride; int dcol; int b0; };

__global__ __launch_bounds__(256)
void cast_all(CSeg c0, CSeg c1, CSeg c2, CSeg c3)
{
  const int bid = blockIdx.x;
  CSeg sg = c0;
  if (bid >= c3.b0) sg = c3; else if (bid >= c2.b0) sg = c2;
  else if (bid >= c1.b0) sg = c1;
  const int tid = (bid - sg.b0) * 256 + threadIdx.x;
  const int row = tid >> sg.qshift;
  const int c   = (tid & ((1 << sg.qshift) - 1)) << 2;
  const int cols = 4 << sg.qshift;
  f32x4 v = *reinterpret_cast<const f32x4*>(sg.s + (size_t)row * cols + c);
  u16x4 o;
  #pragma unroll
  for (int j = 0; j < 4; ++j) o[j] = f32_to_bf16(v[j]);
  *reinterpret_cast<u16x4*>(sg.d + (size_t)row * sg.dstride + sg.dcol + c) = o;
}

// ---------------------------------------------------------------------------
// GRU elementwise: det = z*h + (1-z)*n   (gates [z,r,h], reset_after)
// ---------------------------------------------------------------------------
__global__ __launch_bounds__(256)
void gru_elem(const float* __restrict__ gi, const float* __restrict__ gh,
              const float* __restrict__ h,
              unsigned short* __restrict__ det_bf, int det_stride,
              float* __restrict__ det_out)
{
  const int tid = blockIdx.x * 256 + threadIdx.x;
  const int row = tid >> 9;
  const int c   = (tid & 511) << 2;
  const size_t gb = (size_t)row * 6144 + c;
  f32x4 iz = *reinterpret_cast<const f32x4*>(gi + gb);
  f32x4 hz = *reinterpret_cast<const f32x4*>(gh + gb);
  f32x4 ir = *reinterpret_cast<const f32x4*>(gi + gb + 2048);
  f32x4 hr = *reinterpret_cast<const f32x4*>(gh + gb + 2048);
  f32x4 ih = *reinterpret_cast<const f32x4*>(gi + gb + 4096);
  f32x4 hh = *reinterpret_cast<const f32x4*>(gh + gb + 4096);
  f32x4 hv = *reinterpret_cast<const f32x4*>(h + (size_t)row * 2048 + c);
  f32x4 d;
  u16x4 ob;
  #pragma unroll
  for (int j = 0; j < 4; ++j) {
    const float z = 1.0f / (1.0f + expf(-(iz[j] + hz[j])));
    const float r = 1.0f / (1.0f + expf(-(ir[j] + hr[j])));
    const float n = tanhf(ih[j] + r * hh[j]);
    d[j] = z * hv[j] + (1.0f - z) * n;
    ob[j] = f32_to_bf16(d[j]);
  }
  *reinterpret_cast<u16x4*>(det_bf + (size_t)row * det_stride + c) = ob;
  if (det_out)
    *reinterpret_cast<f32x4*>(det_out + (size_t)row * 8192 + c) = d;
}

// ---------------------------------------------------------------------------
// mu/std/sample epilogue
// ---------------------------------------------------------------------------
__global__ __launch_bounds__(256)
void mu_std_sample(const float* __restrict__ raw, const float* __restrict__ eps,
                   float* __restrict__ out, int mu_off, int std_off, int samp_off)
{
  const int tid = blockIdx.x * 256 + threadIdx.x;
  const int row = tid >> 8;
  const int c   = (tid & 255) << 2;
  f32x4 mu = *reinterpret_cast<const f32x4*>(raw + (size_t)row * 2048 + c);
  f32x4 sp = *reinterpret_cast<const f32x4*>(raw + (size_t)row * 2048 + 1024 + c);
  f32x4 ev = *reinterpret_cast<const f32x4*>(eps + (size_t)row * 1024 + c);
  f32x4 sd, sm;
  #pragma unroll
  for (int j = 0; j < 4; ++j) {
    const float x = sp[j];
    const float s = ((x > 0.0f) ? (x + log1pf(expf(-x))) : log1pf(expf(x))) + 1e-4f;
    sd[j] = s;
    sm[j] = mu[j] + s * ev[j];
  }
  float* ob = out + (size_t)row * 8192;
  *reinterpret_cast<f32x4*>(ob + mu_off   + c) = mu;
  *reinterpret_cast<f32x4*>(ob + std_off  + c) = sd;
  *reinterpret_cast<f32x4*>(ob + samp_off + c) = sm;
}

// bias init for both branches: out[c] = c<1024 ? bmu[c] : bstd[c-1024]
__global__ __launch_bounds__(256)
void bias_init(const float* __restrict__ bmup, const float* __restrict__ bstdp,
               const float* __restrict__ bmuq, const float* __restrict__ bstdq,
               float* __restrict__ bp, float* __restrict__ bq)
{
  const int bid = blockIdx.x;  // 0..15
  const int c = (bid & 7) * 256 + threadIdx.x;
  const float* bmu  = (bid < 8) ? bmup : bmuq;
  const float* bstd = (bid < 8) ? bstdp : bstdq;
  float* o          = (bid < 8) ? bp : bq;
  o[c] = (c < 1024) ? bmu[c] : bstd[c - 1024];
}

// bias[1024+c] += 0.54 * sum_k W[k][c]  (both branches in one dispatch)
__global__ __launch_bounds__(256)
void colsum_add(const float* __restrict__ Wp, const float* __restrict__ Wq,
                float* __restrict__ bp, float* __restrict__ bq)
{
  const int c  = blockIdx.x * 256 + threadIdx.x;  // 0..1023
  const int yy = blockIdx.y;                       // 0..31
  const float* W = (yy < 16) ? Wp : Wq;
  float* bias    = (yy < 16) ? bp : bq;
  const int k0 = (yy & 15) * 128;
  float s = 0.0f;
  for (int k = 0; k < 128; ++k) s += W[(size_t)(k0 + k) * 1024 + c];
  atomicAdd(bias + 1024 + c, 0.54f * s);
}

// ---------------------------------------------------------------------------

extern "C" void kernel_launch(void* const* d_in, const int* in_sizes, int n_in,
                              void* d_out, int out_size, void* d_ws, size_t ws_size,
                              hipStream_t stream)
{
  const float* obs    = (const float*)d_in[0];
  const float* ctx    = (const float*)d_in[1];
  const float* psamp  = (const float*)d_in[2];
  const float* pdet   = (const float*)d_in[3];
  const float* eps_p  = (const float*)d_in[5];
  const float* eps_q  = (const float*)d_in[6];
  const float* W_p1   = (const float*)d_in[7];
  const float* b_p1   = (const float*)d_in[8];
  const float* Wi     = (const float*)d_in[9];
  const float* Wh     = (const float*)d_in[10];
  const float* bi     = (const float*)d_in[11];
  const float* bh     = (const float*)d_in[12];
  const float* W_p2   = (const float*)d_in[13];
  const float* b_p2   = (const float*)d_in[14];
  const float* W_pmu  = (const float*)d_in[15];
  const float* b_pmu  = (const float*)d_in[16];
  const float* W_pstd = (const float*)d_in[17];
  const float* b_pstd = (const float*)d_in[18];
  const float* W_q1   = (const float*)d_in[19];
  const float* b_q1   = (const float*)d_in[20];
  const float* W_q2   = (const float*)d_in[21];
  const float* b_q2   = (const float*)d_in[22];
  const float* W_qmu  = (const float*)d_in[23];
  const float* b_qmu  = (const float*)d_in[24];
  const float* W_qstd = (const float*)d_in[25];
  const float* b_qstd = (const float*)d_in[26];
  float* out = (float*)d_out;

  char* ws = (char*)d_ws;
  size_t off = 0;
  auto alloc = [&](size_t bytes) -> void* {
    void* p = ws + off;
    off += (bytes + 255) & ~(size_t)255;
    return p;
  };
  typedef unsigned short us;
  us* WP1T = (us*)alloc((size_t)2048 * 2048 * 2);
  us* WIT  = (us*)alloc((size_t)6144 * 2048 * 2);
  us* WHT  = (us*)alloc((size_t)6144 * 2048 * 2);
  us* WP2T = (us*)alloc((size_t)2048 * 2048 * 2);
  us* WPST = (us*)alloc((size_t)2048 * 2048 * 2);
  us* WQ1T = (us*)alloc((size_t)2048 * 4096 * 2);
  us* WQ2T = (us*)alloc((size_t)2048 * 2048 * 2);
  us* WQST = (us*)alloc((size_t)2048 * 2048 * 2);
  us* X1   = (us*)alloc((size_t)1024 * 2048 * 2);
  us* X2   = (us*)alloc((size_t)1024 * 4096 * 2);
  us* HBF  = (us*)alloc((size_t)1024 * 2048 * 2);
  us* H1   = (us*)alloc((size_t)1024 * 2048 * 2);
  us* H2   = (us*)alloc((size_t)1024 * 2048 * 2);
  us* DETQ = (us*)alloc((size_t)1024 * 2048 * 2);
  float* GH    = (float*)alloc((size_t)1024 * 6144 * 4);
  float* GI    = (float*)alloc((size_t)1024 * 6144 * 4);
  float* RAW   = (float*)alloc((size_t)1024 * 2048 * 4);
  float* BIASP = (float*)alloc(2048 * 4);
  float* BIASQ = (float*)alloc(2048 * 4);
  (void)ws_size; (void)in_sizes; (void)n_in; (void)out_size;

  const dim3 B256(256);
  const dim3 B512(512);

  // --- fused weight transposes (one dispatch, 13312 blocks) ---
  // tiles: K/64 x N/64 ; kshift = log2(K/64)
  TArgs ta;
  int t0 = 0;
  auto seg = [&](int idx, const float* s, us* d, int N, int K) {
    ta.g[idx] = TSeg{s, d, N, (K == 4096) ? 6 : 5, t0};
    t0 += (K >> 6) * (N >> 6);
  };
  seg(0, W_p1,   WP1T, 2048, 2048);
  seg(1, Wi,     WIT,  6144, 2048);
  seg(2, Wh,     WHT,  6144, 2048);
  seg(3, W_p2,   WP2T, 2048, 2048);
  seg(4, W_pmu,  WPST,               1024, 2048);
  seg(5, W_pstd, WPST + 1024 * 2048, 1024, 2048);
  seg(6, W_q1,   WQ1T, 2048, 4096);
  seg(7, W_q2,   WQ2T, 2048, 2048);
  seg(8, W_qmu,  WQST,               1024, 2048);
  seg(9, W_qstd, WQST + 1024 * 2048, 1024, 2048);
  transpose_all<<<dim3(t0), B256, 0, stream>>>(ta);

  // --- fused activation casts (one dispatch) ---
  CSeg c0{psamp, X1,  8, 2048, 0,    0};
  CSeg c1{ctx,   X1,  8, 2048, 1024, 1024};
  CSeg c2{obs,   X2,  9, 4096, 2048, 2048};
  CSeg c3{pdet,  HBF, 9, 2048, 0,    4096};
  cast_all<<<dim3(6144), B256, 0, stream>>>(c0, c1, c2, c3);

  // --- fused biases: bias + 0.54*colsum(W_std) ---
  bias_init<<<dim3(16), B256, 0, stream>>>(b_pmu, b_pstd, b_qmu, b_qstd, BIASP, BIASQ);
  colsum_add<<<dim3(4, 32), B256, 0, stream>>>(W_pstd, W_qstd, BIASP, BIASQ);

  // --- prior chain ---
  gemm_bt<64, true, true><<<dim3(32, 8), B512, 0, stream>>>(
      X1, 2048, WP1T, b_p1, nullptr, H1, 2048, 2048);                 // h1
  gemm_bt<128, false, false><<<dim3(48, 8), B512, 0, stream>>>(
      HBF, 2048, WHT, bh, GH, nullptr, 6144, 2048);                   // gh (shared)
  gemm_bt<128, false, false><<<dim3(48, 8), B512, 0, stream>>>(
      H1, 2048, WIT, bi, GI, nullptr, 6144, 2048);                    // gi
  gru_elem<<<dim3(2048), B256, 0, stream>>>(GI, GH, pdet, X2, 4096, out + 3072);
  gemm_bt<64, true, true><<<dim3(32, 8), B512, 0, stream>>>(
      X2, 4096, WP2T, b_p2, nullptr, H2, 2048, 2048);                 // h2
  gemm_bt<64, false, false><<<dim3(32, 8), B512, 0, stream>>>(
      H2, 2048, WPST, BIASP, RAW, nullptr, 2048, 2048);               // [mu_p|std_p]
  mu_std_sample<<<dim3(1024), B256, 0, stream>>>(RAW, eps_p, out, 0, 1024, 2048);

  // --- posterior chain ---
  gemm_bt<64, true, true><<<dim3(32, 8), B512, 0, stream>>>(
      X2, 4096, WQ1T, b_q1, nullptr, H1, 2048, 4096);                 // h1q
  gemm_bt<128, false, false><<<dim3(48, 8), B512, 0, stream>>>(
      H1, 2048, WIT, bi, GI, nullptr, 6144, 2048);                    // giq
  gru_elem<<<dim3(2048), B256, 0, stream>>>(GI, GH, pdet, DETQ, 2048, nullptr);
  gemm_bt<64, true, true><<<dim3(32, 8), B512, 0, stream>>>(
      DETQ, 2048, WQ2T, b_q2, nullptr, H2, 2048, 2048);               // h2q
  gemm_bt<64, false, false><<<dim3(32, 8), B512, 0, stream>>>(
      H2, 2048, WQST, BIASQ, RAW, nullptr, 2048, 2048);               // [mu_q|std_q]
  mu_std_sample<<<dim3(1024), B256, 0, stream>>>(RAW, eps_q, out, 5120, 6144, 7168);
}